// Round 5
// baseline (91.137 us; speedup 1.0000x reference)
//
#include <hip/hip_runtime.h>
#include <stdint.h>

// Problem constants (from the reference)
constexpr int BATCH       = 32;
constexpr int NUM_WINDOWS = 1020;
constexpr int FLAT        = 128;   // num_vars * window_size * k
constexpr int VOCAB_ROWS  = 2048;  // power of two -> mod is a mask
constexpr int EMBED_DIM   = 512;
constexpr unsigned long long BIG_PRIME = 17461204521323ull;

// Reference: h=0; for t in flat: h = (h + t + 1) * P   (int64, wrapping)
//   ==> h = sum_{i=0..127} (t_i + 1) * P^(128 - i)   mod 2^64
// (signed wrap == unsigned wrap bitwise). Precompute P^k mod 2^64 at compile time.
struct Pows { unsigned long long v[FLAT + 1]; };
constexpr Pows make_pows() {
    Pows p{};
    p.v[0] = 1ull;
    for (int i = 1; i <= FLAT; ++i) p.v[i] = p.v[i - 1] * BIG_PRIME;
    return p;
}
__constant__ Pows c_pows = make_pows();

// One 64-lane wave per token (32*1020 = 32640 tokens):
//  - lane l loads fuzz[2l], fuzz[2l+1] as int2 (coalesced 512 B/wave; fuzz is int32!)
//  - partial = (t.x+1)*P^(128-2l) + (t.y+1)*P^(127-2l)   (wrapping uint64)
//  - 6-step butterfly shuffle reduce (wrapping adds are associative) -> all lanes hold h
//  - tok = h & 2047 (floored mod by power of two == bitmask on two's complement)
//  - 64 lanes copy the 512-float row as 2 x float4 each (coalesced 2 KiB/wave)
__global__ __launch_bounds__(256) void tokenizer_kernel(
    const int* __restrict__ fuzz,
    const float* __restrict__ emb,
    float* __restrict__ out,
    int n_tokens)
{
    const int gtid = blockIdx.x * blockDim.x + threadIdx.x;
    const int wave = gtid >> 6;
    const int lane = threadIdx.x & 63;
    if (wave >= n_tokens) return;

    const int* base = fuzz + (size_t)wave * FLAT;
    const int2 t = *reinterpret_cast<const int2*>(base + 2 * lane);

    unsigned long long h =
        (unsigned long long)(unsigned)(t.x + 1) * c_pows.v[FLAT - 2 * lane] +
        (unsigned long long)(unsigned)(t.y + 1) * c_pows.v[FLAT - 1 - 2 * lane];

    // Butterfly reduce across the 64-lane wave (wrapping adds are associative).
    #pragma unroll
    for (int off = 32; off > 0; off >>= 1)
        h += (unsigned long long)__shfl_xor((long long)h, off, 64);

    const unsigned tok = (unsigned)(h & (unsigned long long)(VOCAB_ROWS - 1));

    const float4* src = reinterpret_cast<const float4*>(emb + (size_t)tok * EMBED_DIM);
    float4*       dst = reinterpret_cast<float4*>(out + (size_t)wave * EMBED_DIM);
    // 512 floats = 128 float4; 64 lanes x 2
    dst[lane]      = src[lane];
    dst[lane + 64] = src[lane + 64];
}

extern "C" void kernel_launch(void* const* d_in, const int* in_sizes, int n_in,
                              void* d_out, int out_size, void* d_ws, size_t ws_size,
                              hipStream_t stream) {
    const int*   fuzz = (const int*)d_in[0];   // int32 on device (harness converts int64)
    const float* emb  = (const float*)d_in[1]; // f32 [2048,512]
    float*       out  = (float*)d_out;         // f32 [32,1020,512]

    const int n_tokens = BATCH * NUM_WINDOWS;  // 32640 waves
    const int threads  = 256;                  // 4 waves/block
    const int blocks   = (n_tokens * 64 + threads - 1) / threads;  // 8160

    tokenizer_kernel<<<blocks, threads, 0, stream>>>(fuzz, emb, out, n_tokens);
}